// Round 1
// baseline (791.983 us; speedup 1.0000x reference)
//
#include <hip/hip_runtime.h>
#include <math.h>

// Problem constants (from reference): N=100000, F_IN=256, H=128, C=40, E_total=1700000
#define F_IN 256
#define HDIM 128
#define CDIM 40

// ---------------------------------------------------------------------------
// CSR construction
// ---------------------------------------------------------------------------
__global__ __launch_bounds__(256) void k_hist(const int* __restrict__ rows,
                                              int* __restrict__ deg_cnt, int Et) {
    int e = blockIdx.x * 256 + threadIdx.x;
    if (e < Et) atomicAdd(&deg_cnt[rows[e]], 1);
}

__global__ __launch_bounds__(256) void k_chunk_sum(const int* __restrict__ deg_cnt,
                                                   int* __restrict__ chunk_sum, int Nn) {
    __shared__ int sm[256];
    int t = threadIdx.x;
    int i = blockIdx.x * 256 + t;
    sm[t] = (i < Nn) ? deg_cnt[i] : 0;
    __syncthreads();
    for (int o = 128; o > 0; o >>= 1) {
        if (t < o) sm[t] += sm[t + o];
        __syncthreads();
    }
    if (t == 0) chunk_sum[blockIdx.x] = sm[0];
}

// single block, 512 threads, scans chunk sums (NCH <= 512)
__global__ __launch_bounds__(512) void k_scan_chunks(const int* __restrict__ chunk_sum,
                                                     int* __restrict__ chunk_off,
                                                     int* __restrict__ row_ptr,
                                                     int Nn, int nch) {
    __shared__ int sm[512];
    int t = threadIdx.x;
    int v = (t < nch) ? chunk_sum[t] : 0;
    sm[t] = v;
    __syncthreads();
    for (int o = 1; o < 512; o <<= 1) {
        int u = (t >= o) ? sm[t - o] : 0;
        __syncthreads();
        sm[t] += u;
        __syncthreads();
    }
    if (t < nch) chunk_off[t] = sm[t] - v;   // exclusive
    if (t == nch - 1) row_ptr[Nn] = sm[t];   // total edges
}

__global__ __launch_bounds__(256) void k_scan_final(const int* __restrict__ deg_cnt,
                                                    const int* __restrict__ chunk_off,
                                                    int* __restrict__ row_ptr,
                                                    float* __restrict__ deg_inv, int Nn) {
    __shared__ int sm[256];
    int t = threadIdx.x;
    int i = blockIdx.x * 256 + t;
    int d = (i < Nn) ? deg_cnt[i] : 0;
    sm[t] = d;
    __syncthreads();
    for (int o = 1; o < 256; o <<= 1) {
        int u = (t >= o) ? sm[t - o] : 0;
        __syncthreads();
        sm[t] += u;
        __syncthreads();
    }
    if (i < Nn) {
        row_ptr[i] = chunk_off[blockIdx.x] + sm[t] - d;  // exclusive
        deg_inv[i] = (d > 0) ? (1.0f / (float)d) : 0.0f;
    }
}

__global__ __launch_bounds__(256) void k_fill(const int* __restrict__ rows,
                                              const int* __restrict__ cols,
                                              const int* __restrict__ row_ptr,
                                              int* __restrict__ deg_cnt,
                                              int* __restrict__ csr_col, int Et) {
    int e = blockIdx.x * 256 + threadIdx.x;
    if (e < Et) {
        int r = rows[e];
        int pos = row_ptr[r] + atomicSub(&deg_cnt[r], 1) - 1;
        csr_col[pos] = cols[e];
    }
}

// ---------------------------------------------------------------------------
// GEMM1: h1[N,128] = x[N,256] @ W1[256,128] + b1 (f32, tiled, 8x8 microtile)
// tile: 128 rows x 128 cols, KC=32; 256 threads
// ---------------------------------------------------------------------------
#define KC 32
__global__ __launch_bounds__(256) void k_gemm1(const float* __restrict__ x,
                                               const float* __restrict__ W1,
                                               const float* __restrict__ b1,
                                               float* __restrict__ h1, int Nn) {
    __shared__ float As[KC][128];  // transposed x tile: As[k][row]
    __shared__ float Bs[KC][128];  // Bs[k][col]
    int tid = threadIdx.x;
    int tx = tid & 15;
    int ty = tid >> 4;
    int block_row = blockIdx.x * 128;

    float acc[8][8];
#pragma unroll
    for (int i = 0; i < 8; i++)
#pragma unroll
        for (int j = 0; j < 8; j++) acc[i][j] = 0.f;

    for (int kc = 0; kc < F_IN; kc += KC) {
        // load A tile (transposed): thread -> row = tid>>1, k half = (tid&1)*16
        {
            int arow = tid >> 1;
            int grow = block_row + arow;
            int grc = (grow < Nn) ? grow : (Nn - 1);
            int kb = (tid & 1) * 16;
            const float* xp = x + (size_t)grc * F_IN + kc + kb;
            float4 a0 = ((const float4*)xp)[0];
            float4 a1 = ((const float4*)xp)[1];
            float4 a2 = ((const float4*)xp)[2];
            float4 a3 = ((const float4*)xp)[3];
            As[kb + 0][arow] = a0.x;  As[kb + 1][arow] = a0.y;
            As[kb + 2][arow] = a0.z;  As[kb + 3][arow] = a0.w;
            As[kb + 4][arow] = a1.x;  As[kb + 5][arow] = a1.y;
            As[kb + 6][arow] = a1.z;  As[kb + 7][arow] = a1.w;
            As[kb + 8][arow] = a2.x;  As[kb + 9][arow] = a2.y;
            As[kb + 10][arow] = a2.z; As[kb + 11][arow] = a2.w;
            As[kb + 12][arow] = a3.x; As[kb + 13][arow] = a3.y;
            As[kb + 14][arow] = a3.z; As[kb + 15][arow] = a3.w;
        }
        // load B tile: 32 k-rows x 128 cols; 1024 float4 total, 4 per thread
        {
#pragma unroll
            for (int p = 0; p < 4; p++) {
                int idx = p * 256 + tid;        // f4 index over [k][cq]
                int k = idx >> 5;               // 0..31
                int cq = idx & 31;              // 0..31 (col/4)
                float4 v = *(const float4*)&W1[(size_t)(kc + k) * HDIM + cq * 4];
                *(float4*)&Bs[k][cq * 4] = v;
            }
        }
        __syncthreads();
#pragma unroll 8
        for (int k = 0; k < KC; k++) {
            float4 a0 = *(const float4*)&As[k][ty * 4];
            float4 a1 = *(const float4*)&As[k][ty * 4 + 64];
            float4 b0 = *(const float4*)&Bs[k][tx * 4];
            float4 b1v = *(const float4*)&Bs[k][tx * 4 + 64];
            float ar[8] = {a0.x, a0.y, a0.z, a0.w, a1.x, a1.y, a1.z, a1.w};
            float br[8] = {b0.x, b0.y, b0.z, b0.w, b1v.x, b1v.y, b1v.z, b1v.w};
#pragma unroll
            for (int i = 0; i < 8; i++)
#pragma unroll
                for (int j = 0; j < 8; j++) acc[i][j] += ar[i] * br[j];
        }
        __syncthreads();
    }

    float4 bb0 = *(const float4*)&b1[tx * 4];
    float4 bb1 = *(const float4*)&b1[tx * 4 + 64];
#pragma unroll
    for (int i = 0; i < 8; i++) {
        int row = block_row + ((i < 4) ? (ty * 4 + i) : (64 + ty * 4 + i - 4));
        if (row < Nn) {
            float4 o0 = {acc[i][0] + bb0.x, acc[i][1] + bb0.y,
                         acc[i][2] + bb0.z, acc[i][3] + bb0.w};
            float4 o1 = {acc[i][4] + bb1.x, acc[i][5] + bb1.y,
                         acc[i][6] + bb1.z, acc[i][7] + bb1.w};
            *(float4*)&h1[(size_t)row * HDIM + tx * 4] = o0;
            *(float4*)&h1[(size_t)row * HDIM + tx * 4 + 64] = o1;
        }
    }
}

// ---------------------------------------------------------------------------
// Agg1 + ReLU: agg1[i] = relu( (sum_j h1[j]) * deg_inv[i] ), one wave per node
// ---------------------------------------------------------------------------
__global__ __launch_bounds__(256) void k_agg1(const float* __restrict__ h1,
                                              const int* __restrict__ row_ptr,
                                              const int* __restrict__ csr_col,
                                              const float* __restrict__ deg_inv,
                                              float* __restrict__ agg1, int Nn) {
    int wid = threadIdx.x >> 6;
    int lane = threadIdx.x & 63;
    int node = blockIdx.x * 4 + wid;
    if (node >= Nn) return;
    int p0 = row_ptr[node], p1 = row_ptr[node + 1];
    float ax = 0.f, ay = 0.f;
    for (int p = p0; p < p1; p++) {
        int j = csr_col[p];
        float2 v = *(const float2*)&h1[(size_t)j * HDIM + lane * 2];
        ax += v.x;
        ay += v.y;
    }
    float di = deg_inv[node];
    float2 o;
    o.x = fmaxf(ax * di, 0.f);
    o.y = fmaxf(ay * di, 0.f);
    *(float2*)&agg1[(size_t)node * HDIM + lane * 2] = o;
}

// ---------------------------------------------------------------------------
// GEMM2: h2[N,40] = agg1[N,128] @ W2[128,40] + b2
// block: 256 thr = 64 nodes x 4 thr; each thread computes 10 cols
// W2 staged transposed in LDS: Ws[c][k]
// ---------------------------------------------------------------------------
__global__ __launch_bounds__(256) void k_gemm2(const float* __restrict__ a,
                                               const float* __restrict__ W2,
                                               const float* __restrict__ b2,
                                               float* __restrict__ h2, int Nn) {
    __shared__ float Ws[CDIM][HDIM];  // 40*128*4 = 20KB, transposed
    __shared__ float bs[CDIM];
    int tid = threadIdx.x;
    for (int idx = tid; idx < CDIM * HDIM; idx += 256) {
        int c = idx >> 7;      // /128
        int k = idx & 127;
        Ws[c][k] = W2[(size_t)k * CDIM + c];
    }
    if (tid < CDIM) bs[tid] = b2[tid];
    __syncthreads();

    int node = blockIdx.x * 64 + (tid >> 2);
    if (node >= Nn) return;
    int cg = (tid & 3) * 10;

    float acc[10];
#pragma unroll
    for (int c = 0; c < 10; c++) acc[c] = 0.f;

    const float* ap = a + (size_t)node * HDIM;
    for (int k = 0; k < HDIM; k += 4) {
        float4 av = *(const float4*)(ap + k);
#pragma unroll
        for (int c = 0; c < 10; c++) {
            float4 wv = *(const float4*)&Ws[cg + c][k];
            acc[c] += av.x * wv.x + av.y * wv.y + av.z * wv.z + av.w * wv.w;
        }
    }
#pragma unroll
    for (int c = 0; c < 10; c++) h2[(size_t)node * CDIM + cg + c] = acc[c] + bs[cg + c];
}

// ---------------------------------------------------------------------------
// Agg2 + log_softmax: one wave per node, lanes 0..39 hold classes
// ---------------------------------------------------------------------------
__global__ __launch_bounds__(256) void k_agg2_lsm(const float* __restrict__ h2,
                                                  const int* __restrict__ row_ptr,
                                                  const int* __restrict__ csr_col,
                                                  const float* __restrict__ deg_inv,
                                                  float* __restrict__ out, int Nn) {
    int wid = threadIdx.x >> 6;
    int lane = threadIdx.x & 63;
    int node = blockIdx.x * 4 + wid;
    if (node >= Nn) return;
    int p0 = row_ptr[node], p1 = row_ptr[node + 1];
    float acc = 0.f;
    for (int p = p0; p < p1; p++) {
        int j = csr_col[p];
        if (lane < CDIM) acc += h2[(size_t)j * CDIM + lane];
    }
    float di = deg_inv[node];
    float v = acc * di;
    float mval = (lane < CDIM) ? v : -INFINITY;
#pragma unroll
    for (int o = 32; o > 0; o >>= 1) mval = fmaxf(mval, __shfl_xor(mval, o, 64));
    float e = (lane < CDIM) ? __expf(v - mval) : 0.f;
    float s = e;
#pragma unroll
    for (int o = 32; o > 0; o >>= 1) s += __shfl_xor(s, o, 64);
    if (lane < CDIM) out[(size_t)node * CDIM + lane] = v - mval - logf(s);
}

// ---------------------------------------------------------------------------
extern "C" void kernel_launch(void* const* d_in, const int* in_sizes, int n_in,
                              void* d_out, int out_size, void* d_ws, size_t ws_size,
                              hipStream_t stream) {
    const float* x = (const float*)d_in[0];
    const int* edge_index = (const int*)d_in[1];
    const float* W1 = (const float*)d_in[2];
    const float* b1 = (const float*)d_in[3];
    const float* W2 = (const float*)d_in[4];
    const float* b2 = (const float*)d_in[5];
    float* out = (float*)d_out;

    const int Nn = in_sizes[0] / F_IN;       // 100000
    const int Et = in_sizes[1] / 2;          // 1700000
    const int* rows = edge_index;
    const int* cols = edge_index + Et;

    // workspace layout (all offsets multiple of 256B)
    char* ws = (char*)d_ws;
    size_t pN = ((size_t)Nn * 4 + 255) & ~(size_t)255;        // N ints/floats padded
    size_t pNp1 = ((size_t)(Nn + 1) * 4 + 255) & ~(size_t)255;
    size_t pE = ((size_t)Et * 4 + 255) & ~(size_t)255;
    size_t o_deg = 0;
    size_t o_rp = o_deg + pN;
    size_t o_cs = o_rp + pNp1;
    size_t o_co = o_cs + 2048;
    size_t o_dinv = o_co + 2048;
    size_t o_col = o_dinv + pN;
    size_t o_h1 = o_col + pE;
    size_t o_agg = o_h1 + (size_t)Nn * HDIM * 4;
    size_t o_h2 = o_h1;  // alias: h1 dead after agg1, h2 written by gemm2

    int* deg_cnt = (int*)(ws + o_deg);
    int* row_ptr = (int*)(ws + o_rp);
    int* chunk_sum = (int*)(ws + o_cs);
    int* chunk_off = (int*)(ws + o_co);
    float* deg_inv = (float*)(ws + o_dinv);
    int* csr_col = (int*)(ws + o_col);
    float* h1 = (float*)(ws + o_h1);
    float* agg1 = (float*)(ws + o_agg);
    float* h2 = (float*)(ws + o_h2);

    const int nch = (Nn + 255) / 256;  // 391 (<=512)

    hipMemsetAsync(deg_cnt, 0, (size_t)Nn * 4, stream);

    // CSR build
    k_hist<<<(Et + 255) / 256, 256, 0, stream>>>(rows, deg_cnt, Et);
    k_chunk_sum<<<nch, 256, 0, stream>>>(deg_cnt, chunk_sum, Nn);
    k_scan_chunks<<<1, 512, 0, stream>>>(chunk_sum, chunk_off, row_ptr, Nn, nch);
    k_scan_final<<<nch, 256, 0, stream>>>(deg_cnt, chunk_off, row_ptr, deg_inv, Nn);
    k_fill<<<(Et + 255) / 256, 256, 0, stream>>>(rows, cols, row_ptr, deg_cnt, csr_col, Et);

    // layer 1
    k_gemm1<<<(Nn + 127) / 128, 256, 0, stream>>>(x, W1, b1, h1, Nn);
    k_agg1<<<(Nn + 3) / 4, 256, 0, stream>>>(h1, row_ptr, csr_col, deg_inv, agg1, Nn);

    // layer 2
    k_gemm2<<<(Nn + 63) / 64, 256, 0, stream>>>(agg1, W2, b2, h2, Nn);
    k_agg2_lsm<<<(Nn + 3) / 4, 256, 0, stream>>>(h2, row_ptr, csr_col, deg_inv, out, Nn);
}

// Round 2
// 669.381 us; speedup vs baseline: 1.1832x; 1.1832x over previous
//
#include <hip/hip_runtime.h>
#include <math.h>

// Problem constants: N=100000, F_IN=256, H=128, C=40, E_total=1700000
#define F_IN 256
#define HDIM 128
#define CDIM 40

typedef unsigned int uint;
typedef unsigned short ushort;

__device__ __forceinline__ ushort f2bf(float f) {
    uint u = __float_as_uint(f);
    uint r = (u + 0x7fffu + ((u >> 16) & 1u)) >> 16;   // RNE
    return (ushort)r;
}
__device__ __forceinline__ float bf2f(ushort h) {
    return __uint_as_float(((uint)h) << 16);
}

// ---------------------------------------------------------------------------
// CSR construction
// ---------------------------------------------------------------------------
__global__ __launch_bounds__(256) void k_hist(const int* __restrict__ rows,
                                              int* __restrict__ deg_cnt, int Et) {
    int e = blockIdx.x * 256 + threadIdx.x;
    if (e < Et) atomicAdd(&deg_cnt[rows[e]], 1);
}

__global__ __launch_bounds__(256) void k_chunk_sum(const int* __restrict__ deg_cnt,
                                                   int* __restrict__ chunk_sum, int Nn) {
    __shared__ int sm[256];
    int t = threadIdx.x;
    int i = blockIdx.x * 256 + t;
    sm[t] = (i < Nn) ? deg_cnt[i] : 0;
    __syncthreads();
    for (int o = 128; o > 0; o >>= 1) {
        if (t < o) sm[t] += sm[t + o];
        __syncthreads();
    }
    if (t == 0) chunk_sum[blockIdx.x] = sm[0];
}

__global__ __launch_bounds__(512) void k_scan_chunks(const int* __restrict__ chunk_sum,
                                                     int* __restrict__ chunk_off,
                                                     int* __restrict__ row_ptr,
                                                     int Nn, int nch) {
    __shared__ int sm[512];
    int t = threadIdx.x;
    int v = (t < nch) ? chunk_sum[t] : 0;
    sm[t] = v;
    __syncthreads();
    for (int o = 1; o < 512; o <<= 1) {
        int u = (t >= o) ? sm[t - o] : 0;
        __syncthreads();
        sm[t] += u;
        __syncthreads();
    }
    if (t < nch) chunk_off[t] = sm[t] - v;   // exclusive
    if (t == nch - 1) row_ptr[Nn] = sm[t];
}

__global__ __launch_bounds__(256) void k_scan_final(const int* __restrict__ deg_cnt,
                                                    const int* __restrict__ chunk_off,
                                                    int* __restrict__ row_ptr,
                                                    float* __restrict__ deg_inv, int Nn) {
    __shared__ int sm[256];
    int t = threadIdx.x;
    int i = blockIdx.x * 256 + t;
    int d = (i < Nn) ? deg_cnt[i] : 0;
    sm[t] = d;
    __syncthreads();
    for (int o = 1; o < 256; o <<= 1) {
        int u = (t >= o) ? sm[t - o] : 0;
        __syncthreads();
        sm[t] += u;
        __syncthreads();
    }
    if (i < Nn) {
        row_ptr[i] = chunk_off[blockIdx.x] + sm[t] - d;  // exclusive
        deg_inv[i] = (d > 0) ? (1.0f / (float)d) : 0.0f;
    }
}

__global__ __launch_bounds__(256) void k_fill(const int* __restrict__ rows,
                                              const int* __restrict__ cols,
                                              const int* __restrict__ row_ptr,
                                              int* __restrict__ deg_cnt,
                                              int* __restrict__ csr_col, int Et) {
    int e = blockIdx.x * 256 + threadIdx.x;
    if (e < Et) {
        int r = rows[e];
        int pos = row_ptr[r] + atomicSub(&deg_cnt[r], 1) - 1;
        csr_col[pos] = cols[e];
    }
}

// ---------------------------------------------------------------------------
// GEMM1: h1[N,128](bf16) = x[N,256] @ W1[256,128] + b1 (f32 accum)
// ---------------------------------------------------------------------------
#define KC 32
__global__ __launch_bounds__(256) void k_gemm1(const float* __restrict__ x,
                                               const float* __restrict__ W1,
                                               const float* __restrict__ b1,
                                               ushort* __restrict__ h1, int Nn) {
    __shared__ float As[KC][128];
    __shared__ float Bs[KC][128];
    int tid = threadIdx.x;
    int tx = tid & 15;
    int ty = tid >> 4;
    int block_row = blockIdx.x * 128;

    float acc[8][8];
#pragma unroll
    for (int i = 0; i < 8; i++)
#pragma unroll
        for (int j = 0; j < 8; j++) acc[i][j] = 0.f;

    for (int kc = 0; kc < F_IN; kc += KC) {
        {
            int arow = tid >> 1;
            int grow = block_row + arow;
            int grc = (grow < Nn) ? grow : (Nn - 1);
            int kb = (tid & 1) * 16;
            const float* xp = x + (size_t)grc * F_IN + kc + kb;
            float4 a0 = ((const float4*)xp)[0];
            float4 a1 = ((const float4*)xp)[1];
            float4 a2 = ((const float4*)xp)[2];
            float4 a3 = ((const float4*)xp)[3];
            As[kb + 0][arow] = a0.x;  As[kb + 1][arow] = a0.y;
            As[kb + 2][arow] = a0.z;  As[kb + 3][arow] = a0.w;
            As[kb + 4][arow] = a1.x;  As[kb + 5][arow] = a1.y;
            As[kb + 6][arow] = a1.z;  As[kb + 7][arow] = a1.w;
            As[kb + 8][arow] = a2.x;  As[kb + 9][arow] = a2.y;
            As[kb + 10][arow] = a2.z; As[kb + 11][arow] = a2.w;
            As[kb + 12][arow] = a3.x; As[kb + 13][arow] = a3.y;
            As[kb + 14][arow] = a3.z; As[kb + 15][arow] = a3.w;
        }
        {
#pragma unroll
            for (int p = 0; p < 4; p++) {
                int idx = p * 256 + tid;
                int k = idx >> 5;
                int cq = idx & 31;
                float4 v = *(const float4*)&W1[(size_t)(kc + k) * HDIM + cq * 4];
                *(float4*)&Bs[k][cq * 4] = v;
            }
        }
        __syncthreads();
#pragma unroll 8
        for (int k = 0; k < KC; k++) {
            float4 a0 = *(const float4*)&As[k][ty * 4];
            float4 a1 = *(const float4*)&As[k][ty * 4 + 64];
            float4 b0 = *(const float4*)&Bs[k][tx * 4];
            float4 b1v = *(const float4*)&Bs[k][tx * 4 + 64];
            float ar[8] = {a0.x, a0.y, a0.z, a0.w, a1.x, a1.y, a1.z, a1.w};
            float br[8] = {b0.x, b0.y, b0.z, b0.w, b1v.x, b1v.y, b1v.z, b1v.w};
#pragma unroll
            for (int i = 0; i < 8; i++)
#pragma unroll
                for (int j = 0; j < 8; j++) acc[i][j] += ar[i] * br[j];
        }
        __syncthreads();
    }

    float4 bb0 = *(const float4*)&b1[tx * 4];
    float4 bb1 = *(const float4*)&b1[tx * 4 + 64];
#pragma unroll
    for (int i = 0; i < 8; i++) {
        int row = block_row + ((i < 4) ? (ty * 4 + i) : (64 + ty * 4 + i - 4));
        if (row < Nn) {
            ushort4 o0, o1;
            o0.x = f2bf(acc[i][0] + bb0.x); o0.y = f2bf(acc[i][1] + bb0.y);
            o0.z = f2bf(acc[i][2] + bb0.z); o0.w = f2bf(acc[i][3] + bb0.w);
            o1.x = f2bf(acc[i][4] + bb1.x); o1.y = f2bf(acc[i][5] + bb1.y);
            o1.z = f2bf(acc[i][6] + bb1.z); o1.w = f2bf(acc[i][7] + bb1.w);
            *(ushort4*)&h1[(size_t)row * HDIM + tx * 4] = o0;
            *(ushort4*)&h1[(size_t)row * HDIM + tx * 4 + 64] = o1;
        }
    }
}

// ---------------------------------------------------------------------------
// Agg1 + ReLU: bf16 gather (256B/row), preloaded indices, f32 accum, bf16 out
// one wave per node; lane l covers cols 2l, 2l+1
// ---------------------------------------------------------------------------
__global__ __launch_bounds__(256) void k_agg1(const ushort* __restrict__ h1,
                                              const int* __restrict__ row_ptr,
                                              const int* __restrict__ csr_col,
                                              const float* __restrict__ deg_inv,
                                              ushort* __restrict__ agg1, int Nn) {
    int wid = threadIdx.x >> 6;
    int lane = threadIdx.x & 63;
    int node = blockIdx.x * 4 + wid;
    if (node >= Nn) return;
    int p0 = row_ptr[node], p1 = row_ptr[node + 1];
    int deg = p1 - p0;
    float ax = 0.f, ay = 0.f;
    for (int base = 0; base < deg; base += 64) {
        int li = base + lane;
        int idx = (li < deg) ? csr_col[p0 + li] : 0;
        int cnt = min(64, deg - base);
#pragma unroll 4
        for (int p = 0; p < cnt; p++) {
            int j = __shfl(idx, p, 64);
            uint v = *(const uint*)&h1[(size_t)j * HDIM + lane * 2];
            ax += __uint_as_float(v << 16);
            ay += __uint_as_float(v & 0xffff0000u);
        }
    }
    float di = deg_inv[node];
    ushort2 o;
    o.x = f2bf(fmaxf(ax * di, 0.f));
    o.y = f2bf(fmaxf(ay * di, 0.f));
    *(ushort2*)&agg1[(size_t)node * HDIM + lane * 2] = o;
}

// ---------------------------------------------------------------------------
// GEMM2: h2[N,40](bf16) = agg1[N,128](bf16) @ W2[128,40] + b2 (f32 accum)
// 256 thr = 64 nodes x 4 thr; each thread 10 cols; W2 transposed in LDS
// ---------------------------------------------------------------------------
__global__ __launch_bounds__(256) void k_gemm2(const ushort* __restrict__ a,
                                               const float* __restrict__ W2,
                                               const float* __restrict__ b2,
                                               ushort* __restrict__ h2, int Nn) {
    __shared__ float Ws[CDIM][HDIM];  // transposed: Ws[c][k]
    __shared__ float bs[CDIM];
    int tid = threadIdx.x;
    for (int idx = tid; idx < CDIM * HDIM; idx += 256) {
        int c = idx >> 7;
        int k = idx & 127;
        Ws[c][k] = W2[(size_t)k * CDIM + c];
    }
    if (tid < CDIM) bs[tid] = b2[tid];
    __syncthreads();

    int node = blockIdx.x * 64 + (tid >> 2);
    if (node >= Nn) return;
    int cg = (tid & 3) * 10;

    float acc[10];
#pragma unroll
    for (int c = 0; c < 10; c++) acc[c] = 0.f;

    const uint2* ap = (const uint2*)(a + (size_t)node * HDIM);
    for (int k = 0; k < HDIM; k += 4) {
        uint2 av = ap[k >> 2];
        float a0 = __uint_as_float(av.x << 16);
        float a1 = __uint_as_float(av.x & 0xffff0000u);
        float a2 = __uint_as_float(av.y << 16);
        float a3 = __uint_as_float(av.y & 0xffff0000u);
#pragma unroll
        for (int c = 0; c < 10; c++) {
            float4 wv = *(const float4*)&Ws[cg + c][k];
            acc[c] += a0 * wv.x + a1 * wv.y + a2 * wv.z + a3 * wv.w;
        }
    }
#pragma unroll
    for (int c = 0; c < 10; c++)
        h2[(size_t)node * CDIM + cg + c] = f2bf(acc[c] + bs[cg + c]);
}

// ---------------------------------------------------------------------------
// Agg2 + log_softmax: bf16 gather (80B/row), preloaded indices
// one wave per node, lanes 0..39 hold classes
// ---------------------------------------------------------------------------
__global__ __launch_bounds__(256) void k_agg2_lsm(const ushort* __restrict__ h2,
                                                  const int* __restrict__ row_ptr,
                                                  const int* __restrict__ csr_col,
                                                  const float* __restrict__ deg_inv,
                                                  float* __restrict__ out, int Nn) {
    int wid = threadIdx.x >> 6;
    int lane = threadIdx.x & 63;
    int node = blockIdx.x * 4 + wid;
    if (node >= Nn) return;
    int p0 = row_ptr[node], p1 = row_ptr[node + 1];
    int deg = p1 - p0;
    float acc = 0.f;
    for (int base = 0; base < deg; base += 64) {
        int li = base + lane;
        int idx = (li < deg) ? csr_col[p0 + li] : 0;
        int cnt = min(64, deg - base);
#pragma unroll 4
        for (int p = 0; p < cnt; p++) {
            int j = __shfl(idx, p, 64);
            if (lane < CDIM) acc += bf2f(h2[(size_t)j * CDIM + lane]);
        }
    }
    float di = deg_inv[node];
    float v = acc * di;
    float mval = (lane < CDIM) ? v : -INFINITY;
#pragma unroll
    for (int o = 32; o > 0; o >>= 1) mval = fmaxf(mval, __shfl_xor(mval, o, 64));
    float e = (lane < CDIM) ? __expf(v - mval) : 0.f;
    float s = e;
#pragma unroll
    for (int o = 32; o > 0; o >>= 1) s += __shfl_xor(s, o, 64);
    if (lane < CDIM) out[(size_t)node * CDIM + lane] = v - mval - logf(s);
}

// ---------------------------------------------------------------------------
extern "C" void kernel_launch(void* const* d_in, const int* in_sizes, int n_in,
                              void* d_out, int out_size, void* d_ws, size_t ws_size,
                              hipStream_t stream) {
    const float* x = (const float*)d_in[0];
    const int* edge_index = (const int*)d_in[1];
    const float* W1 = (const float*)d_in[2];
    const float* b1 = (const float*)d_in[3];
    const float* W2 = (const float*)d_in[4];
    const float* b2 = (const float*)d_in[5];
    float* out = (float*)d_out;

    const int Nn = in_sizes[0] / F_IN;       // 100000
    const int Et = in_sizes[1] / 2;          // 1700000
    const int* rows = edge_index;
    const int* cols = edge_index + Et;

    char* ws = (char*)d_ws;
    size_t pN = ((size_t)Nn * 4 + 255) & ~(size_t)255;
    size_t pNp1 = ((size_t)(Nn + 1) * 4 + 255) & ~(size_t)255;
    size_t pE = ((size_t)Et * 4 + 255) & ~(size_t)255;
    size_t pH1 = ((size_t)Nn * HDIM * 2 + 255) & ~(size_t)255;   // bf16
    size_t o_deg = 0;
    size_t o_rp = o_deg + pN;
    size_t o_cs = o_rp + pNp1;
    size_t o_co = o_cs + 2048;
    size_t o_dinv = o_co + 2048;
    size_t o_col = o_dinv + pN;
    size_t o_h1 = o_col + pE;
    size_t o_agg = o_h1 + pH1;
    size_t o_h2 = o_h1;  // alias: h1 dead after agg1

    int* deg_cnt = (int*)(ws + o_deg);
    int* row_ptr = (int*)(ws + o_rp);
    int* chunk_sum = (int*)(ws + o_cs);
    int* chunk_off = (int*)(ws + o_co);
    float* deg_inv = (float*)(ws + o_dinv);
    int* csr_col = (int*)(ws + o_col);
    ushort* h1 = (ushort*)(ws + o_h1);
    ushort* agg1 = (ushort*)(ws + o_agg);
    ushort* h2 = (ushort*)(ws + o_h2);

    const int nch = (Nn + 255) / 256;

    hipMemsetAsync(deg_cnt, 0, (size_t)Nn * 4, stream);

    k_hist<<<(Et + 255) / 256, 256, 0, stream>>>(rows, deg_cnt, Et);
    k_chunk_sum<<<nch, 256, 0, stream>>>(deg_cnt, chunk_sum, Nn);
    k_scan_chunks<<<1, 512, 0, stream>>>(chunk_sum, chunk_off, row_ptr, Nn, nch);
    k_scan_final<<<nch, 256, 0, stream>>>(deg_cnt, chunk_off, row_ptr, deg_inv, Nn);
    k_fill<<<(Et + 255) / 256, 256, 0, stream>>>(rows, cols, row_ptr, deg_cnt, csr_col, Et);

    k_gemm1<<<(Nn + 127) / 128, 256, 0, stream>>>(x, W1, b1, h1, Nn);
    k_agg1<<<(Nn + 3) / 4, 256, 0, stream>>>(h1, row_ptr, csr_col, deg_inv, agg1, Nn);

    k_gemm2<<<(Nn + 63) / 64, 256, 0, stream>>>(agg1, W2, b2, h2, Nn);
    k_agg2_lsm<<<(Nn + 3) / 4, 256, 0, stream>>>(h2, row_ptr, csr_col, deg_inv, out, Nn);
}

// Round 4
// 567.271 us; speedup vs baseline: 1.3961x; 1.1800x over previous
//
#include <hip/hip_runtime.h>
#include <math.h>

// Problem constants: N=100000, F_IN=256, H=128, C=40, E_total=1700000
#define F_IN 256
#define HDIM 128
#define CDIM 40

typedef unsigned int uint;
typedef unsigned short ushort;

__device__ __forceinline__ ushort f2bf(float f) {
    uint u = __float_as_uint(f);
    uint r = (u + 0x7fffu + ((u >> 16) & 1u)) >> 16;   // RNE
    return (ushort)r;
}
__device__ __forceinline__ float bf2f(ushort h) {
    return __uint_as_float(((uint)h) << 16);
}

// ---------------------------------------------------------------------------
// CSR construction
// ---------------------------------------------------------------------------
__global__ __launch_bounds__(256) void k_hist(const int* __restrict__ rows,
                                              int* __restrict__ deg_cnt, int Et) {
    int e = blockIdx.x * 256 + threadIdx.x;
    if (e < Et) atomicAdd(&deg_cnt[rows[e]], 1);
}

__global__ __launch_bounds__(256) void k_chunk_sum(const int* __restrict__ deg_cnt,
                                                   int* __restrict__ chunk_sum, int Nn) {
    __shared__ int sm[256];
    int t = threadIdx.x;
    int i = blockIdx.x * 256 + t;
    sm[t] = (i < Nn) ? deg_cnt[i] : 0;
    __syncthreads();
    for (int o = 128; o > 0; o >>= 1) {
        if (t < o) sm[t] += sm[t + o];
        __syncthreads();
    }
    if (t == 0) chunk_sum[blockIdx.x] = sm[0];
}

__global__ __launch_bounds__(512) void k_scan_chunks(const int* __restrict__ chunk_sum,
                                                     int* __restrict__ chunk_off,
                                                     int* __restrict__ row_ptr,
                                                     int Nn, int nch) {
    __shared__ int sm[512];
    int t = threadIdx.x;
    int v = (t < nch) ? chunk_sum[t] : 0;
    sm[t] = v;
    __syncthreads();
    for (int o = 1; o < 512; o <<= 1) {
        int u = (t >= o) ? sm[t - o] : 0;
        __syncthreads();
        sm[t] += u;
        __syncthreads();
    }
    if (t < nch) chunk_off[t] = sm[t] - v;   // exclusive
    if (t == nch - 1) row_ptr[Nn] = sm[t];
}

__global__ __launch_bounds__(256) void k_scan_final(const int* __restrict__ deg_cnt,
                                                    const int* __restrict__ chunk_off,
                                                    int* __restrict__ row_ptr,
                                                    float* __restrict__ deg_inv, int Nn) {
    __shared__ int sm[256];
    int t = threadIdx.x;
    int i = blockIdx.x * 256 + t;
    int d = (i < Nn) ? deg_cnt[i] : 0;
    sm[t] = d;
    __syncthreads();
    for (int o = 1; o < 256; o <<= 1) {
        int u = (t >= o) ? sm[t - o] : 0;
        __syncthreads();
        sm[t] += u;
        __syncthreads();
    }
    if (i < Nn) {
        row_ptr[i] = chunk_off[blockIdx.x] + sm[t] - d;  // exclusive
        deg_inv[i] = (d > 0) ? (1.0f / (float)d) : 0.0f;
    }
}

__global__ __launch_bounds__(256) void k_fill(const int* __restrict__ rows,
                                              const int* __restrict__ cols,
                                              const int* __restrict__ row_ptr,
                                              int* __restrict__ deg_cnt,
                                              int* __restrict__ csr_col, int Et) {
    int e = blockIdx.x * 256 + threadIdx.x;
    if (e < Et) {
        int r = rows[e];
        int pos = row_ptr[r] + atomicSub(&deg_cnt[r], 1) - 1;
        csr_col[pos] = cols[e];
    }
}

// ---------------------------------------------------------------------------
// GEMM1: h1[N,128](bf16) = x[N,256] @ W1[256,128] + b1 (f32 accum)
// ---------------------------------------------------------------------------
#define KC 32
__global__ __launch_bounds__(256) void k_gemm1(const float* __restrict__ x,
                                               const float* __restrict__ W1,
                                               const float* __restrict__ b1,
                                               ushort* __restrict__ h1, int Nn) {
    __shared__ float As[KC][128];
    __shared__ float Bs[KC][128];
    int tid = threadIdx.x;
    int tx = tid & 15;
    int ty = tid >> 4;
    int block_row = blockIdx.x * 128;

    float acc[8][8];
#pragma unroll
    for (int i = 0; i < 8; i++)
#pragma unroll
        for (int j = 0; j < 8; j++) acc[i][j] = 0.f;

    for (int kc = 0; kc < F_IN; kc += KC) {
        {
            int arow = tid >> 1;
            int grow = block_row + arow;
            int grc = (grow < Nn) ? grow : (Nn - 1);
            int kb = (tid & 1) * 16;
            const float* xp = x + (size_t)grc * F_IN + kc + kb;
            float4 a0 = ((const float4*)xp)[0];
            float4 a1 = ((const float4*)xp)[1];
            float4 a2 = ((const float4*)xp)[2];
            float4 a3 = ((const float4*)xp)[3];
            As[kb + 0][arow] = a0.x;  As[kb + 1][arow] = a0.y;
            As[kb + 2][arow] = a0.z;  As[kb + 3][arow] = a0.w;
            As[kb + 4][arow] = a1.x;  As[kb + 5][arow] = a1.y;
            As[kb + 6][arow] = a1.z;  As[kb + 7][arow] = a1.w;
            As[kb + 8][arow] = a2.x;  As[kb + 9][arow] = a2.y;
            As[kb + 10][arow] = a2.z; As[kb + 11][arow] = a2.w;
            As[kb + 12][arow] = a3.x; As[kb + 13][arow] = a3.y;
            As[kb + 14][arow] = a3.z; As[kb + 15][arow] = a3.w;
        }
        {
#pragma unroll
            for (int p = 0; p < 4; p++) {
                int idx = p * 256 + tid;
                int k = idx >> 5;
                int cq = idx & 31;
                float4 v = *(const float4*)&W1[(size_t)(kc + k) * HDIM + cq * 4];
                *(float4*)&Bs[k][cq * 4] = v;
            }
        }
        __syncthreads();
#pragma unroll 8
        for (int k = 0; k < KC; k++) {
            float4 a0 = *(const float4*)&As[k][ty * 4];
            float4 a1 = *(const float4*)&As[k][ty * 4 + 64];
            float4 b0 = *(const float4*)&Bs[k][tx * 4];
            float4 b1v = *(const float4*)&Bs[k][tx * 4 + 64];
            float ar[8] = {a0.x, a0.y, a0.z, a0.w, a1.x, a1.y, a1.z, a1.w};
            float br[8] = {b0.x, b0.y, b0.z, b0.w, b1v.x, b1v.y, b1v.z, b1v.w};
#pragma unroll
            for (int i = 0; i < 8; i++)
#pragma unroll
                for (int j = 0; j < 8; j++) acc[i][j] += ar[i] * br[j];
        }
        __syncthreads();
    }

    float4 bb0 = *(const float4*)&b1[tx * 4];
    float4 bb1 = *(const float4*)&b1[tx * 4 + 64];
#pragma unroll
    for (int i = 0; i < 8; i++) {
        int row = block_row + ((i < 4) ? (ty * 4 + i) : (64 + ty * 4 + i - 4));
        if (row < Nn) {
            ushort4 o0, o1;
            o0.x = f2bf(acc[i][0] + bb0.x); o0.y = f2bf(acc[i][1] + bb0.y);
            o0.z = f2bf(acc[i][2] + bb0.z); o0.w = f2bf(acc[i][3] + bb0.w);
            o1.x = f2bf(acc[i][4] + bb1.x); o1.y = f2bf(acc[i][5] + bb1.y);
            o1.z = f2bf(acc[i][6] + bb1.z); o1.w = f2bf(acc[i][7] + bb1.w);
            *(ushort4*)&h1[(size_t)row * HDIM + tx * 4] = o0;
            *(ushort4*)&h1[(size_t)row * HDIM + tx * 4 + 64] = o1;
        }
    }
}

// ---------------------------------------------------------------------------
// Agg1 + ReLU: 4 edge-groups x 16 lanes, uint4 (8 bf16 cols) per lane.
// 4 gathers in flight per iteration; combine groups via shfl_xor 16/32.
// ---------------------------------------------------------------------------
__global__ __launch_bounds__(256) void k_agg1(const ushort* __restrict__ h1,
                                              const int* __restrict__ row_ptr,
                                              const int* __restrict__ csr_col,
                                              const float* __restrict__ deg_inv,
                                              ushort* __restrict__ agg1, int Nn) {
    int wid = threadIdx.x >> 6;
    int lane = threadIdx.x & 63;
    int node = blockIdx.x * 4 + wid;
    if (node >= Nn) return;
    int p0 = row_ptr[node], p1 = row_ptr[node + 1];
    int deg = p1 - p0;
    int g = lane >> 4;   // edge group 0..3
    int q = lane & 15;   // col chunk: cols 8q..8q+7

    float acc[8];
#pragma unroll
    for (int i = 0; i < 8; i++) acc[i] = 0.f;

    for (int base = 0; base < deg; base += 64) {
        int li = base + lane;
        int cache = (li < deg) ? csr_col[p0 + li] : 0;
        int cnt = min(64, deg - base);
        if (cnt == 64) {
#pragma unroll 4
            for (int t = 0; t < 16; t++) {
                int j = __shfl(cache, 4 * t + g, 64);
                uint4 v = *(const uint4*)&h1[(size_t)j * HDIM + q * 8];
                acc[0] += __uint_as_float(v.x << 16);
                acc[1] += __uint_as_float(v.x & 0xffff0000u);
                acc[2] += __uint_as_float(v.y << 16);
                acc[3] += __uint_as_float(v.y & 0xffff0000u);
                acc[4] += __uint_as_float(v.z << 16);
                acc[5] += __uint_as_float(v.z & 0xffff0000u);
                acc[6] += __uint_as_float(v.w << 16);
                acc[7] += __uint_as_float(v.w & 0xffff0000u);
            }
        } else {
            int steps = (cnt + 3) >> 2;
            for (int t = 0; t < steps; t++) {
                int ei = 4 * t + g;
                bool act = ei < cnt;
                int j = __shfl(cache, act ? ei : 0, 64);
                uint4 v = *(const uint4*)&h1[(size_t)j * HDIM + q * 8];
                float w = act ? 1.f : 0.f;
                acc[0] += w * __uint_as_float(v.x << 16);
                acc[1] += w * __uint_as_float(v.x & 0xffff0000u);
                acc[2] += w * __uint_as_float(v.y << 16);
                acc[3] += w * __uint_as_float(v.y & 0xffff0000u);
                acc[4] += w * __uint_as_float(v.z << 16);
                acc[5] += w * __uint_as_float(v.z & 0xffff0000u);
                acc[6] += w * __uint_as_float(v.w << 16);
                acc[7] += w * __uint_as_float(v.w & 0xffff0000u);
            }
        }
    }
#pragma unroll
    for (int i = 0; i < 8; i++) acc[i] += __shfl_xor(acc[i], 16, 64);
#pragma unroll
    for (int i = 0; i < 8; i++) acc[i] += __shfl_xor(acc[i], 32, 64);

    if (g == 0) {
        float di = deg_inv[node];
        uint4 o;
        o.x = (uint)f2bf(fmaxf(acc[0] * di, 0.f)) | ((uint)f2bf(fmaxf(acc[1] * di, 0.f)) << 16);
        o.y = (uint)f2bf(fmaxf(acc[2] * di, 0.f)) | ((uint)f2bf(fmaxf(acc[3] * di, 0.f)) << 16);
        o.z = (uint)f2bf(fmaxf(acc[4] * di, 0.f)) | ((uint)f2bf(fmaxf(acc[5] * di, 0.f)) << 16);
        o.w = (uint)f2bf(fmaxf(acc[6] * di, 0.f)) | ((uint)f2bf(fmaxf(acc[7] * di, 0.f)) << 16);
        *(uint4*)&agg1[(size_t)node * HDIM + q * 8] = o;
    }
}

// ---------------------------------------------------------------------------
// GEMM2: h2[N,40](bf16) = agg1[N,128](bf16) @ W2[128,40] + b2 (f32 accum)
// ---------------------------------------------------------------------------
__global__ __launch_bounds__(256) void k_gemm2(const ushort* __restrict__ a,
                                               const float* __restrict__ W2,
                                               const float* __restrict__ b2,
                                               ushort* __restrict__ h2, int Nn) {
    __shared__ float Ws[CDIM][HDIM];  // transposed: Ws[c][k]
    __shared__ float bs[CDIM];
    int tid = threadIdx.x;
    for (int idx = tid; idx < CDIM * HDIM; idx += 256) {
        int c = idx >> 7;
        int k = idx & 127;
        Ws[c][k] = W2[(size_t)k * CDIM + c];
    }
    if (tid < CDIM) bs[tid] = b2[tid];
    __syncthreads();

    int node = blockIdx.x * 64 + (tid >> 2);
    if (node >= Nn) return;
    int cg = (tid & 3) * 10;

    float acc[10];
#pragma unroll
    for (int c = 0; c < 10; c++) acc[c] = 0.f;

    const uint2* ap = (const uint2*)(a + (size_t)node * HDIM);
    for (int k = 0; k < HDIM; k += 4) {
        uint2 av = ap[k >> 2];
        float a0 = __uint_as_float(av.x << 16);
        float a1 = __uint_as_float(av.x & 0xffff0000u);
        float a2 = __uint_as_float(av.y << 16);
        float a3 = __uint_as_float(av.y & 0xffff0000u);
#pragma unroll
        for (int c = 0; c < 10; c++) {
            float4 wv = *(const float4*)&Ws[cg + c][k];
            acc[c] += a0 * wv.x + a1 * wv.y + a2 * wv.z + a3 * wv.w;
        }
    }
#pragma unroll
    for (int c = 0; c < 10; c++)
        h2[(size_t)node * CDIM + cg + c] = f2bf(acc[c] + bs[cg + c]);
}

// ---------------------------------------------------------------------------
// Agg2 + log_softmax: 6 edge-groups x 10 lanes, uint2 (4 classes) per lane.
// Group-combine into lanes 0..9, width-16 softmax reduce, float4 out.
// ---------------------------------------------------------------------------
__global__ __launch_bounds__(256) void k_agg2_lsm(const ushort* __restrict__ h2,
                                                  const int* __restrict__ row_ptr,
                                                  const int* __restrict__ csr_col,
                                                  const float* __restrict__ deg_inv,
                                                  float* __restrict__ out, int Nn) {
    int wid = threadIdx.x >> 6;
    int lane = threadIdx.x & 63;
    int node = blockIdx.x * 4 + wid;
    if (node >= Nn) return;
    int p0 = row_ptr[node], p1 = row_ptr[node + 1];
    int deg = p1 - p0;
    int g = lane / 10;        // edge group 0..5 (g==6: lanes 60..63 idle)
    int q = lane - g * 10;    // class chunk: classes 4q..4q+3
    bool act_lane = (g < 6);

    float a0 = 0.f, a1 = 0.f, a2 = 0.f, a3 = 0.f;
    for (int base = 0; base < deg; base += 64) {
        int li = base + lane;
        int cache = (li < deg) ? csr_col[p0 + li] : 0;
        int cnt = min(64, deg - base);
#pragma unroll 2
        for (int t = 0; t * 6 < cnt; t++) {
            int ei = t * 6 + g;
            bool act = act_lane && (ei < cnt);
            int j = __shfl(cache, act ? ei : 0, 64);
            uint2 v = *(const uint2*)&h2[(size_t)j * CDIM + q * 4];
            float w = act ? 1.f : 0.f;
            a0 += w * __uint_as_float(v.x << 16);
            a1 += w * __uint_as_float(v.x & 0xffff0000u);
            a2 += w * __uint_as_float(v.y << 16);
            a3 += w * __uint_as_float(v.y & 0xffff0000u);
        }
    }
    // combine the 6 groups into lanes 0..9 (sum of shfl'd originals)
    float s0 = a0, s1 = a1, s2 = a2, s3 = a3;
#pragma unroll
    for (int d = 1; d < 6; d++) {
        int src = (lane + d * 10) & 63;
        s0 += __shfl(a0, src, 64);
        s1 += __shfl(a1, src, 64);
        s2 += __shfl(a2, src, 64);
        s3 += __shfl(a3, src, 64);
    }
    float di = deg_inv[node];
    float v0 = s0 * di, v1 = s1 * di, v2 = s2 * di, v3 = s3 * di;
    bool head = (lane < 10);
    float m = head ? fmaxf(fmaxf(v0, v1), fmaxf(v2, v3)) : -INFINITY;
#pragma unroll
    for (int o = 8; o > 0; o >>= 1) m = fmaxf(m, __shfl_xor(m, o, 16));
    float s = head ? (__expf(v0 - m) + __expf(v1 - m) + __expf(v2 - m) + __expf(v3 - m)) : 0.f;
#pragma unroll
    for (int o = 8; o > 0; o >>= 1) s += __shfl_xor(s, o, 16);
    if (head) {
        float ls = logf(s) + m;
        float4 o4 = {v0 - ls, v1 - ls, v2 - ls, v3 - ls};
        *(float4*)&out[(size_t)node * CDIM + q * 4] = o4;
    }
}

// ---------------------------------------------------------------------------
extern "C" void kernel_launch(void* const* d_in, const int* in_sizes, int n_in,
                              void* d_out, int out_size, void* d_ws, size_t ws_size,
                              hipStream_t stream) {
    const float* x = (const float*)d_in[0];
    const int* edge_index = (const int*)d_in[1];
    const float* W1 = (const float*)d_in[2];
    const float* b1 = (const float*)d_in[3];
    const float* W2 = (const float*)d_in[4];
    const float* b2 = (const float*)d_in[5];
    float* out = (float*)d_out;

    const int Nn = in_sizes[0] / F_IN;       // 100000
    const int Et = in_sizes[1] / 2;          // 1700000
    const int* rows = edge_index;
    const int* cols = edge_index + Et;

    char* ws = (char*)d_ws;
    size_t pN = ((size_t)Nn * 4 + 255) & ~(size_t)255;
    size_t pNp1 = ((size_t)(Nn + 1) * 4 + 255) & ~(size_t)255;
    size_t pE = ((size_t)Et * 4 + 255) & ~(size_t)255;
    size_t pH1 = ((size_t)Nn * HDIM * 2 + 255) & ~(size_t)255;   // bf16
    size_t o_deg = 0;
    size_t o_rp = o_deg + pN;
    size_t o_cs = o_rp + pNp1;
    size_t o_co = o_cs + 2048;
    size_t o_dinv = o_co + 2048;
    size_t o_col = o_dinv + pN;
    size_t o_h1 = o_col + pE;
    size_t o_agg = o_h1 + pH1;
    size_t o_h2 = o_h1;  // alias: h1 dead after agg1

    int* deg_cnt = (int*)(ws + o_deg);
    int* row_ptr = (int*)(ws + o_rp);
    int* chunk_sum = (int*)(ws + o_cs);
    int* chunk_off = (int*)(ws + o_co);
    float* deg_inv = (float*)(ws + o_dinv);
    int* csr_col = (int*)(ws + o_col);
    ushort* h1 = (ushort*)(ws + o_h1);
    ushort* agg1 = (ushort*)(ws + o_agg);
    ushort* h2 = (ushort*)(ws + o_h2);

    const int nch = (Nn + 255) / 256;

    hipMemsetAsync(deg_cnt, 0, (size_t)Nn * 4, stream);

    k_hist<<<(Et + 255) / 256, 256, 0, stream>>>(rows, deg_cnt, Et);
    k_chunk_sum<<<nch, 256, 0, stream>>>(deg_cnt, chunk_sum, Nn);
    k_scan_chunks<<<1, 512, 0, stream>>>(chunk_sum, chunk_off, row_ptr, Nn, nch);
    k_scan_final<<<nch, 256, 0, stream>>>(deg_cnt, chunk_off, row_ptr, deg_inv, Nn);
    k_fill<<<(Et + 255) / 256, 256, 0, stream>>>(rows, cols, row_ptr, deg_cnt, csr_col, Et);

    k_gemm1<<<(Nn + 127) / 128, 256, 0, stream>>>(x, W1, b1, h1, Nn);
    k_agg1<<<(Nn + 3) / 4, 256, 0, stream>>>(h1, row_ptr, csr_col, deg_inv, agg1, Nn);

    k_gemm2<<<(Nn + 63) / 64, 256, 0, stream>>>(agg1, W2, b2, h2, Nn);
    k_agg2_lsm<<<(Nn + 3) / 4, 256, 0, stream>>>(h2, row_ptr, csr_col, deg_inv, out, Nn);
}

// Round 6
// 531.759 us; speedup vs baseline: 1.4894x; 1.0668x over previous
//
#include <hip/hip_runtime.h>
#include <math.h>

// Problem constants: N=100000, F_IN=256, H=128, C=40, E_total=1700000
#define F_IN 256
#define HDIM 128
#define CDIM 40

typedef unsigned int uint;
typedef unsigned short ushort;
typedef short short8v __attribute__((ext_vector_type(8)));
typedef float f32x4 __attribute__((ext_vector_type(4)));

__device__ __forceinline__ ushort f2bf(float f) {
    uint u = __float_as_uint(f);
    uint r = (u + 0x7fffu + ((u >> 16) & 1u)) >> 16;   // RNE
    return (ushort)r;
}
__device__ __forceinline__ float bf2f(ushort h) {
    return __uint_as_float(((uint)h) << 16);
}

// ---------------------------------------------------------------------------
// CSR construction
// ---------------------------------------------------------------------------
__global__ __launch_bounds__(256) void k_hist(const int* __restrict__ rows,
                                              int* __restrict__ deg_cnt, int Et) {
    int e = blockIdx.x * 256 + threadIdx.x;
    if (e < Et) atomicAdd(&deg_cnt[rows[e]], 1);
}

__global__ __launch_bounds__(256) void k_chunk_sum(const int* __restrict__ deg_cnt,
                                                   int* __restrict__ chunk_sum, int Nn) {
    __shared__ int sm[256];
    int t = threadIdx.x;
    int i = blockIdx.x * 256 + t;
    sm[t] = (i < Nn) ? deg_cnt[i] : 0;
    __syncthreads();
    for (int o = 128; o > 0; o >>= 1) {
        if (t < o) sm[t] += sm[t + o];
        __syncthreads();
    }
    if (t == 0) chunk_sum[blockIdx.x] = sm[0];
}

__global__ __launch_bounds__(512) void k_scan_chunks(const int* __restrict__ chunk_sum,
                                                     int* __restrict__ chunk_off,
                                                     int* __restrict__ row_ptr,
                                                     int Nn, int nch) {
    __shared__ int sm[512];
    int t = threadIdx.x;
    int v = (t < nch) ? chunk_sum[t] : 0;
    sm[t] = v;
    __syncthreads();
    for (int o = 1; o < 512; o <<= 1) {
        int u = (t >= o) ? sm[t - o] : 0;
        __syncthreads();
        sm[t] += u;
        __syncthreads();
    }
    if (t < nch) chunk_off[t] = sm[t] - v;   // exclusive
    if (t == nch - 1) row_ptr[Nn] = sm[t];
}

__global__ __launch_bounds__(256) void k_scan_final(const int* __restrict__ deg_cnt,
                                                    const int* __restrict__ chunk_off,
                                                    int* __restrict__ row_ptr,
                                                    float* __restrict__ deg_inv, int Nn) {
    __shared__ int sm[256];
    int t = threadIdx.x;
    int i = blockIdx.x * 256 + t;
    int d = (i < Nn) ? deg_cnt[i] : 0;
    sm[t] = d;
    __syncthreads();
    for (int o = 1; o < 256; o <<= 1) {
        int u = (t >= o) ? sm[t - o] : 0;
        __syncthreads();
        sm[t] += u;
        __syncthreads();
    }
    if (i < Nn) {
        row_ptr[i] = chunk_off[blockIdx.x] + sm[t] - d;  // exclusive
        deg_inv[i] = (d > 0) ? (1.0f / (float)d) : 0.0f;
    }
}

__global__ __launch_bounds__(256) void k_fill(const int* __restrict__ rows,
                                              const int* __restrict__ cols,
                                              const int* __restrict__ row_ptr,
                                              int* __restrict__ deg_cnt,
                                              int* __restrict__ csr_col, int Et) {
    int e = blockIdx.x * 256 + threadIdx.x;
    if (e < Et) {
        int r = rows[e];
        int pos = row_ptr[r] + atomicSub(&deg_cnt[r], 1) - 1;
        csr_col[pos] = cols[e];
    }
}

// ---------------------------------------------------------------------------
// W1 transpose+convert: Wt[n][k] (bf16) = W1[k][n] (f32). 64 KB, run once.
// ---------------------------------------------------------------------------
__global__ __launch_bounds__(256) void k_w1t(const float* __restrict__ W1,
                                             ushort* __restrict__ Wt) {
    int idx = blockIdx.x * 256 + threadIdx.x;
    if (idx < F_IN * HDIM) {
        int k = idx >> 7;        // 0..255
        int n = idx & 127;       // coalesced read over n
        Wt[n * F_IN + k] = f2bf(W1[idx]);
    }
}

// ---------------------------------------------------------------------------
// GEMM1 (MFMA bf16): h1[N,128](bf16) = x[N,256] @ W1 + b1, f32 accum.
// 256 thr = 4 waves; block tile 128x128, K-step 64.
// Wave w: rows 32w..32w+31 (2 row-frags), all 128 cols (8 col-frags).
// LDS stride 72 ushorts (144 B): bank spread 4*row mod 32, worst 2-way (free).
// A/B frags use the same lane->k map (kq*8+j), so the K-sum is layout-safe;
// C/D map is the HW-verified col=lane&15, row=(lane>>4)*4+reg.
// ---------------------------------------------------------------------------
#define LDK 72
__global__ __launch_bounds__(256) void k_gemm1(const float* __restrict__ x,
                                               const ushort* __restrict__ Wt,
                                               const float* __restrict__ b1,
                                               ushort* __restrict__ h1, int Nn) {
    __shared__ ushort Ax[128 * LDK];
    __shared__ ushort Bx[128 * LDK];
    int tid = threadIdx.x;
    int w = tid >> 6, l = tid & 63;
    int brow = blockIdx.x * 128;
    int rl = l & 15, kq = l >> 4;

    f32x4 acc[2][8];
#pragma unroll
    for (int m = 0; m < 2; m++)
#pragma unroll
        for (int f = 0; f < 8; f++) acc[m][f] = (f32x4){0.f, 0.f, 0.f, 0.f};

    for (int kk = 0; kk < F_IN; kk += 64) {
        // stage A tile: 128 rows x 64 k (f32 -> bf16), 8 float4 per thread
#pragma unroll
        for (int i = 0; i < 8; i++) {
            int idx = i * 256 + tid;       // 0..2047
            int row = idx >> 4;            // 0..127
            int f4 = idx & 15;             // 0..15
            int gr = brow + row;
            gr = (gr < Nn) ? gr : (Nn - 1);
            float4 v = *(const float4*)&x[(size_t)gr * F_IN + kk + f4 * 4];
            ushort4 u;
            u.x = f2bf(v.x); u.y = f2bf(v.y); u.z = f2bf(v.z); u.w = f2bf(v.w);
            *(ushort4*)&Ax[row * LDK + f4 * 4] = u;
        }
        // stage B tile: 128 n-rows x 64 k (bf16 copy), 4 x 16B per thread
#pragma unroll
        for (int i = 0; i < 4; i++) {
            int idx = i * 256 + tid;       // 0..1023
            int n = idx >> 3;              // 0..127
            int s = idx & 7;               // 0..7
            uint4 v = *(const uint4*)&Wt[n * F_IN + kk + s * 8];
            *(uint4*)&Bx[n * LDK + s * 8] = v;
        }
        __syncthreads();
#pragma unroll
        for (int kf = 0; kf < 2; kf++) {
            short8v a0 = *(const short8v*)&Ax[(w * 32 + rl) * LDK + kf * 32 + kq * 8];
            short8v a1 = *(const short8v*)&Ax[(w * 32 + 16 + rl) * LDK + kf * 32 + kq * 8];
#pragma unroll
            for (int f = 0; f < 8; f++) {
                short8v b = *(const short8v*)&Bx[(f * 16 + rl) * LDK + kf * 32 + kq * 8];
                acc[0][f] = __builtin_amdgcn_mfma_f32_16x16x32_bf16(a0, b, acc[0][f], 0, 0, 0);
                acc[1][f] = __builtin_amdgcn_mfma_f32_16x16x32_bf16(a1, b, acc[1][f], 0, 0, 0);
            }
        }
        __syncthreads();
    }
    // epilogue: bias + bf16 store
#pragma unroll
    for (int f = 0; f < 8; f++) {
        float bias = b1[f * 16 + rl];
#pragma unroll
        for (int m = 0; m < 2; m++) {
#pragma unroll
            for (int r = 0; r < 4; r++) {
                int row = brow + w * 32 + m * 16 + kq * 4 + r;
                if (row < Nn)
                    h1[(size_t)row * HDIM + f * 16 + rl] = f2bf(acc[m][f][r] + bias);
            }
        }
    }
}

// ---------------------------------------------------------------------------
// Agg1 + ReLU: 4 edge-groups x 16 lanes, uint4 (8 bf16 cols) per lane.
// ---------------------------------------------------------------------------
__global__ __launch_bounds__(256) void k_agg1(const ushort* __restrict__ h1,
                                              const int* __restrict__ row_ptr,
                                              const int* __restrict__ csr_col,
                                              const float* __restrict__ deg_inv,
                                              ushort* __restrict__ agg1, int Nn) {
    int wid = threadIdx.x >> 6;
    int lane = threadIdx.x & 63;
    int node = blockIdx.x * 4 + wid;
    if (node >= Nn) return;
    int p0 = row_ptr[node], p1 = row_ptr[node + 1];
    int deg = p1 - p0;
    int g = lane >> 4;   // edge group 0..3
    int q = lane & 15;   // col chunk: cols 8q..8q+7

    float acc[8];
#pragma unroll
    for (int i = 0; i < 8; i++) acc[i] = 0.f;

    for (int base = 0; base < deg; base += 64) {
        int li = base + lane;
        int cache = (li < deg) ? csr_col[p0 + li] : 0;
        int cnt = min(64, deg - base);
        if (cnt == 64) {
#pragma unroll 4
            for (int t = 0; t < 16; t++) {
                int j = __shfl(cache, 4 * t + g, 64);
                uint4 v = *(const uint4*)&h1[(size_t)j * HDIM + q * 8];
                acc[0] += __uint_as_float(v.x << 16);
                acc[1] += __uint_as_float(v.x & 0xffff0000u);
                acc[2] += __uint_as_float(v.y << 16);
                acc[3] += __uint_as_float(v.y & 0xffff0000u);
                acc[4] += __uint_as_float(v.z << 16);
                acc[5] += __uint_as_float(v.z & 0xffff0000u);
                acc[6] += __uint_as_float(v.w << 16);
                acc[7] += __uint_as_float(v.w & 0xffff0000u);
            }
        } else {
            int steps = (cnt + 3) >> 2;
            for (int t = 0; t < steps; t++) {
                int ei = 4 * t + g;
                bool act = ei < cnt;
                int j = __shfl(cache, act ? ei : 0, 64);
                uint4 v = *(const uint4*)&h1[(size_t)j * HDIM + q * 8];
                float w = act ? 1.f : 0.f;
                acc[0] += w * __uint_as_float(v.x << 16);
                acc[1] += w * __uint_as_float(v.x & 0xffff0000u);
                acc[2] += w * __uint_as_float(v.y << 16);
                acc[3] += w * __uint_as_float(v.y & 0xffff0000u);
                acc[4] += w * __uint_as_float(v.z << 16);
                acc[5] += w * __uint_as_float(v.z & 0xffff0000u);
                acc[6] += w * __uint_as_float(v.w << 16);
                acc[7] += w * __uint_as_float(v.w & 0xffff0000u);
            }
        }
    }
#pragma unroll
    for (int i = 0; i < 8; i++) acc[i] += __shfl_xor(acc[i], 16, 64);
#pragma unroll
    for (int i = 0; i < 8; i++) acc[i] += __shfl_xor(acc[i], 32, 64);

    if (g == 0) {
        float di = deg_inv[node];
        uint4 o;
        o.x = (uint)f2bf(fmaxf(acc[0] * di, 0.f)) | ((uint)f2bf(fmaxf(acc[1] * di, 0.f)) << 16);
        o.y = (uint)f2bf(fmaxf(acc[2] * di, 0.f)) | ((uint)f2bf(fmaxf(acc[3] * di, 0.f)) << 16);
        o.z = (uint)f2bf(fmaxf(acc[4] * di, 0.f)) | ((uint)f2bf(fmaxf(acc[5] * di, 0.f)) << 16);
        o.w = (uint)f2bf(fmaxf(acc[6] * di, 0.f)) | ((uint)f2bf(fmaxf(acc[7] * di, 0.f)) << 16);
        *(uint4*)&agg1[(size_t)node * HDIM + q * 8] = o;
    }
}

// ---------------------------------------------------------------------------
// GEMM2: h2[N,40](bf16) = agg1[N,128](bf16) @ W2[128,40] + b2 (f32 accum)
// ---------------------------------------------------------------------------
__global__ __launch_bounds__(256) void k_gemm2(const ushort* __restrict__ a,
                                               const float* __restrict__ W2,
                                               const float* __restrict__ b2,
                                               ushort* __restrict__ h2, int Nn) {
    __shared__ float Ws[CDIM][HDIM];  // transposed: Ws[c][k]
    __shared__ float bs[CDIM];
    int tid = threadIdx.x;
    for (int idx = tid; idx < CDIM * HDIM; idx += 256) {
        int c = idx >> 7;
        int k = idx & 127;
        Ws[c][k] = W2[(size_t)k * CDIM + c];
    }
    if (tid < CDIM) bs[tid] = b2[tid];
    __syncthreads();

    int node = blockIdx.x * 64 + (tid >> 2);
    if (node >= Nn) return;
    int cg = (tid & 3) * 10;

    float acc[10];
#pragma unroll
    for (int c = 0; c < 10; c++) acc[c] = 0.f;

    const uint2* ap = (const uint2*)(a + (size_t)node * HDIM);
    for (int k = 0; k < HDIM; k += 4) {
        uint2 av = ap[k >> 2];
        float a0 = __uint_as_float(av.x << 16);
        float a1 = __uint_as_float(av.x & 0xffff0000u);
        float a2 = __uint_as_float(av.y << 16);
        float a3 = __uint_as_float(av.y & 0xffff0000u);
#pragma unroll
        for (int c = 0; c < 10; c++) {
            float4 wv = *(const float4*)&Ws[cg + c][k];
            acc[c] += a0 * wv.x + a1 * wv.y + a2 * wv.z + a3 * wv.w;
        }
    }
#pragma unroll
    for (int c = 0; c < 10; c++)
        h2[(size_t)node * CDIM + cg + c] = f2bf(acc[c] + bs[cg + c]);
}

// ---------------------------------------------------------------------------
// Agg2 + log_softmax: 6 edge-groups x 10 lanes, uint2 (4 classes) per lane.
// ---------------------------------------------------------------------------
__global__ __launch_bounds__(256) void k_agg2_lsm(const ushort* __restrict__ h2,
                                                  const int* __restrict__ row_ptr,
                                                  const int* __restrict__ csr_col,
                                                  const float* __restrict__ deg_inv,
                                                  float* __restrict__ out, int Nn) {
    int wid = threadIdx.x >> 6;
    int lane = threadIdx.x & 63;
    int node = blockIdx.x * 4 + wid;
    if (node >= Nn) return;
    int p0 = row_ptr[node], p1 = row_ptr[node + 1];
    int deg = p1 - p0;
    int g = lane / 10;        // edge group 0..5 (lanes 60..63 idle)
    int q = lane - g * 10;    // class chunk: classes 4q..4q+3
    bool act_lane = (g < 6);

    float a0 = 0.f, a1 = 0.f, a2 = 0.f, a3 = 0.f;
    for (int base = 0; base < deg; base += 64) {
        int li = base + lane;
        int cache = (li < deg) ? csr_col[p0 + li] : 0;
        int cnt = min(64, deg - base);
#pragma unroll 2
        for (int t = 0; t * 6 < cnt; t++) {
            int ei = t * 6 + g;
            bool act = act_lane && (ei < cnt);
            int j = __shfl(cache, act ? ei : 0, 64);
            uint2 v = *(const uint2*)&h2[(size_t)j * CDIM + q * 4];
            float w = act ? 1.f : 0.f;
            a0 += w * __uint_as_float(v.x << 16);
            a1 += w * __uint_as_float(v.x & 0xffff0000u);
            a2 += w * __uint_as_float(v.y << 16);
            a3 += w * __uint_as_float(v.y & 0xffff0000u);
        }
    }
    float s0 = a0, s1 = a1, s2 = a2, s3 = a3;
#pragma unroll
    for (int d = 1; d < 6; d++) {
        int src = (lane + d * 10) & 63;
        s0 += __shfl(a0, src, 64);
        s1 += __shfl(a1, src, 64);
        s2 += __shfl(a2, src, 64);
        s3 += __shfl(a3, src, 64);
    }
    float di = deg_inv[node];
    float v0 = s0 * di, v1 = s1 * di, v2 = s2 * di, v3 = s3 * di;
    bool head = (lane < 10);
    float m = head ? fmaxf(fmaxf(v0, v1), fmaxf(v2, v3)) : -INFINITY;
#pragma unroll
    for (int o = 8; o > 0; o >>= 1) m = fmaxf(m, __shfl_xor(m, o, 16));
    float s = head ? (__expf(v0 - m) + __expf(v1 - m) + __expf(v2 - m) + __expf(v3 - m)) : 0.f;
#pragma unroll
    for (int o = 8; o > 0; o >>= 1) s += __shfl_xor(s, o, 16);
    if (head) {
        float ls = logf(s) + m;
        float4 o4 = {v0 - ls, v1 - ls, v2 - ls, v3 - ls};
        *(float4*)&out[(size_t)node * CDIM + q * 4] = o4;
    }
}

// ---------------------------------------------------------------------------
extern "C" void kernel_launch(void* const* d_in, const int* in_sizes, int n_in,
                              void* d_out, int out_size, void* d_ws, size_t ws_size,
                              hipStream_t stream) {
    const float* x = (const float*)d_in[0];
    const int* edge_index = (const int*)d_in[1];
    const float* W1 = (const float*)d_in[2];
    const float* b1 = (const float*)d_in[3];
    const float* W2 = (const float*)d_in[4];
    const float* b2 = (const float*)d_in[5];
    float* out = (float*)d_out;

    const int Nn = in_sizes[0] / F_IN;       // 100000
    const int Et = in_sizes[1] / 2;          // 1700000
    const int* rows = edge_index;
    const int* cols = edge_index + Et;

    char* ws = (char*)d_ws;
    size_t pN = ((size_t)Nn * 4 + 255) & ~(size_t)255;
    size_t pNp1 = ((size_t)(Nn + 1) * 4 + 255) & ~(size_t)255;
    size_t pE = ((size_t)Et * 4 + 255) & ~(size_t)255;
    size_t pH1 = ((size_t)Nn * HDIM * 2 + 255) & ~(size_t)255;   // bf16
    size_t o_deg = 0;
    size_t o_rp = o_deg + pN;
    size_t o_cs = o_rp + pNp1;
    size_t o_co = o_cs + 2048;
    size_t o_dinv = o_co + 2048;
    size_t o_col = o_dinv + pN;
    size_t o_h1 = o_col + pE;
    size_t o_agg = o_h1 + pH1;
    size_t o_w1t = o_agg + pH1;
    size_t o_h2 = o_h1;  // alias: h1 dead after agg1

    int* deg_cnt = (int*)(ws + o_deg);
    int* row_ptr = (int*)(ws + o_rp);
    int* chunk_sum = (int*)(ws + o_cs);
    int* chunk_off = (int*)(ws + o_co);
    float* deg_inv = (float*)(ws + o_dinv);
    int* csr_col = (int*)(ws + o_col);
    ushort* h1 = (ushort*)(ws + o_h1);
    ushort* agg1 = (ushort*)(ws + o_agg);
    ushort* w1t = (ushort*)(ws + o_w1t);
    ushort* h2 = (ushort*)(ws + o_h2);

    const int nch = (Nn + 255) / 256;

    hipMemsetAsync(deg_cnt, 0, (size_t)Nn * 4, stream);

    k_hist<<<(Et + 255) / 256, 256, 0, stream>>>(rows, deg_cnt, Et);
    k_chunk_sum<<<nch, 256, 0, stream>>>(deg_cnt, chunk_sum, Nn);
    k_scan_chunks<<<1, 512, 0, stream>>>(chunk_sum, chunk_off, row_ptr, Nn, nch);
    k_scan_final<<<nch, 256, 0, stream>>>(deg_cnt, chunk_off, row_ptr, deg_inv, Nn);
    k_fill<<<(Et + 255) / 256, 256, 0, stream>>>(rows, cols, row_ptr, deg_cnt, csr_col, Et);

    k_w1t<<<(F_IN * HDIM + 255) / 256, 256, 0, stream>>>(W1, w1t);
    k_gemm1<<<(Nn + 127) / 128, 256, 0, stream>>>(x, w1t, b1, h1, Nn);
    k_agg1<<<(Nn + 3) / 4, 256, 0, stream>>>(h1, row_ptr, csr_col, deg_inv, agg1, Nn);

    k_gemm2<<<(Nn + 63) / 64, 256, 0, stream>>>(agg1, W2, b2, h2, Nn);
    k_agg2_lsm<<<(Nn + 3) / 4, 256, 0, stream>>>(h2, row_ptr, csr_col, deg_inv, out, Nn);
}